// Round 9
// baseline (276.528 us; speedup 1.0000x reference)
//
#include <hip/hip_runtime.h>
#include <hip/hip_bf16.h>

#define S_LEN 4096
#define E_DIM 512
#define B_DIM 2
#define M_ROWS (B_DIM * S_LEN)   // 8192

typedef __attribute__((ext_vector_type(8))) short short8;   // 8 bf16 = 4 VGPRs
typedef __attribute__((ext_vector_type(4))) float floatx4;  // MFMA C/D

__device__ __forceinline__ unsigned short f2bf(float f) {
    unsigned u = __float_as_uint(f);
    unsigned r = (u + 0x7fffu + ((u >> 16) & 1u)) >> 16;   // RNE
    return (unsigned short)r;
}
__device__ __forceinline__ float bf2f(unsigned short u) {
    return __uint_as_float((unsigned)u << 16);
}

// async 16B/lane global->LDS (lds dest = wave-uniform base + lane*16)
__device__ __forceinline__ void async_copy16(unsigned short* lds, const unsigned short* g) {
    auto gp = (const __attribute__((address_space(1))) unsigned int*)g;
    auto lp = (__attribute__((address_space(3))) unsigned int*)lds;
    __builtin_amdgcn_global_load_lds(gp, lp, 16, 0, 0);
}

struct MapArg { unsigned short m[640]; };   // encode t | ch<<7 | bb<<9

// ---------------- convert fp32 inputs -> bf16 workspace ----------------
__global__ __launch_bounds__(256) void convert_bf16(
    const float* __restrict__ x,  const float* __restrict__ wq,
    const float* __restrict__ wk, const float* __restrict__ wv,
    const float* __restrict__ wo, unsigned short* __restrict__ dst)
{
    long i = (long)blockIdx.x * 1024 + (long)threadIdx.x * 4;
    const float* src; long off;
    if      (i < 4194304) { src = x;  off = i; }
    else if (i < 4456448) { src = wq; off = i - 4194304; }
    else if (i < 4718592) { src = wk; off = i - 4456448; }
    else if (i < 4980736) { src = wv; off = i - 4718592; }
    else                  { src = wo; off = i - 4980736; }
    float4 v = *(const float4*)(src + off);
    ushort4 o;
    o.x = f2bf(v.x); o.y = f2bf(v.y); o.z = f2bf(v.z); o.w = f2bf(v.w);
    *(ushort4*)(dst + i) = o;
}

// ---------------- MFMA GEMM core: C[m,n] = sum_k A[m,k]*W[n,k] ----------------
__device__ __forceinline__ void gemm_core(
    const unsigned short* __restrict__ A, const unsigned short* __restrict__ W,
    void* __restrict__ Cv, const float* __restrict__ bias, int mode,
    int m0, int n0)
{
    __shared__ unsigned short As[128 * 32];
    __shared__ unsigned short Bs[128 * 32];
    const int tid = threadIdx.x;
    const int lane = tid & 63, wave = tid >> 6;
    const int wm = wave >> 1, wn = wave & 1;
    const int q4 = lane >> 4, l16 = lane & 15;

    floatx4 acc[4][4];
#pragma unroll
    for (int i = 0; i < 4; ++i)
#pragma unroll
        for (int j = 0; j < 4; ++j) acc[i][j] = (floatx4){0.f, 0.f, 0.f, 0.f};

    const int srow = lane >> 2;
    const int scol = (lane & 3) * 8;

    for (int k0 = 0; k0 < 512; k0 += 32) {
        async_copy16(&As[(wave * 16) * 32],
                     A + (size_t)(m0 + wave * 16 + srow) * 512 + k0 + scol);
        async_copy16(&As[(64 + wave * 16) * 32],
                     A + (size_t)(m0 + 64 + wave * 16 + srow) * 512 + k0 + scol);
        async_copy16(&Bs[(wave * 16) * 32],
                     W + (size_t)(n0 + wave * 16 + srow) * 512 + k0 + scol);
        async_copy16(&Bs[(64 + wave * 16) * 32],
                     W + (size_t)(n0 + 64 + wave * 16 + srow) * 512 + k0 + scol);
        __syncthreads();
        short8 af[4], bfr[4];
#pragma unroll
        for (int i = 0; i < 4; ++i) {
            af[i]  = *(const short8*)&As[(wm * 64 + i * 16 + l16) * 32 + q4 * 8];
            bfr[i] = *(const short8*)&Bs[(wn * 64 + i * 16 + l16) * 32 + q4 * 8];
        }
#pragma unroll
        for (int i = 0; i < 4; ++i)
#pragma unroll
            for (int j = 0; j < 4; ++j)
                acc[i][j] = __builtin_amdgcn_mfma_f32_16x16x32_bf16(af[i], bfr[j], acc[i][j], 0, 0, 0);
        __syncthreads();
    }

    if (mode == 0) {
        unsigned short* C = (unsigned short*)Cv;
#pragma unroll
        for (int i = 0; i < 4; ++i) {
            int rowb = m0 + wm * 64 + i * 16 + q4 * 4;
#pragma unroll
            for (int j = 0; j < 4; ++j) {
                int col = n0 + wn * 64 + j * 16 + l16;
#pragma unroll
                for (int rg = 0; rg < 4; ++rg)
                    C[(size_t)(rowb + rg) * 512 + col] = f2bf(acc[i][j][rg]);
            }
        }
    } else if (mode == 1) {
        unsigned short* C = (unsigned short*)Cv;
#pragma unroll
        for (int i = 0; i < 4; ++i) {
            int grow = m0 + wm * 64 + i * 16 + q4 * 4;
            int b = grow >> 12, s = grow & 4095;
#pragma unroll
            for (int j = 0; j < 4; ++j) {
                int e = n0 + wn * 64 + j * 16 + l16;
                ushort4 pk;
                pk.x = f2bf(acc[i][j][0]); pk.y = f2bf(acc[i][j][1]);
                pk.z = f2bf(acc[i][j][2]); pk.w = f2bf(acc[i][j][3]);
                *(ushort4*)(C + (size_t)b * 512 * 4096 + (size_t)e * 4096 + s) = pk;
            }
        }
    } else {
        float* C = (float*)Cv;
#pragma unroll
        for (int i = 0; i < 4; ++i) {
            int rowb = m0 + wm * 64 + i * 16 + q4 * 4;
#pragma unroll
            for (int j = 0; j < 4; ++j) {
                int col = n0 + wn * 64 + j * 16 + l16;
                float bv = bias[col];
#pragma unroll
                for (int rg = 0; rg < 4; ++rg)
                    C[(size_t)(rowb + rg) * 512 + col] = acc[i][j][rg] + bv;
            }
        }
    }
}

__global__ __launch_bounds__(256) void gemm_qkv(
    const unsigned short* __restrict__ xb,
    const unsigned short* __restrict__ Wqb, const unsigned short* __restrict__ Wkb,
    const unsigned short* __restrict__ Wvb,
    unsigned short* __restrict__ Qb, unsigned short* __restrict__ Kb,
    unsigned short* __restrict__ Vtb)
{
    const int z = blockIdx.z;
    const unsigned short* W = (z == 0) ? Wqb : (z == 1) ? Wkb : Wvb;
    unsigned short* C = (z == 0) ? Qb : (z == 1) ? Kb : Vtb;
    gemm_core(xb, W, C, nullptr, (z == 2) ? 1 : 0, blockIdx.y * 128, blockIdx.x * 128);
}

__global__ __launch_bounds__(256) void gemm_out(
    const unsigned short* __restrict__ AOb, const unsigned short* __restrict__ Wob,
    const float* __restrict__ bo, float* __restrict__ out)
{
    gemm_core(AOb, Wob, out, bo, 2, blockIdx.y * 128, blockIdx.x * 128);
}

// ---------------- MFMA flash attention, Tm=32, Tn=32, 512 thr, low-VGPR ----------------
// Anti-causal (keep j >= i). 640 live (tile,batch,chunk-of-1024) blocks via map.
// 8 waves = 4 dim-slices x 2 key-strips for QK (S^T orientation, b128 Sred store);
// PV split-N 64 cols/wave. Fixed softmax ref. Target <=128 unified regs ->
// 4 waves/SIMD = 2 blocks/CU co-resident (the latency-hiding lever).
__global__ __launch_bounds__(512, 4) void flash_mfma(
    const unsigned short* __restrict__ Qg, const unsigned short* __restrict__ Kg,
    const unsigned short* __restrict__ Vt,
    unsigned short* __restrict__ Oh, float* __restrict__ Lb, MapArg map)
{
    const int enc = map.m[blockIdx.x];
    const int tile = enc & 127, ch = (enc >> 7) & 3, bb = enc >> 9;
    const int i0 = tile * 32;
    const int lo0 = 1024 * ch, hi = 1024 * ch + 1024;
    const int lo = (i0 > lo0) ? i0 : lo0;

    const int tid = threadIdx.x;
    const int lane = tid & 63, w = tid >> 6;
    const int s = w & 3, h = w >> 2;          // dim-slice (128 dims), key-strip (16 keys)
    const int q4 = lane >> 4, l16 = lane & 15;
    const float scale = 0.044194173824159216f;  // 1/sqrt(512)
    const float MREF = 4.0f;

    __shared__ float Sred[4][32][36];         // 18.4 KB fp32 S^T partials
    __shared__ unsigned short Plds[32][40];   // 2.6 KB P bf16
    __shared__ float Lred[32][16];

    const size_t rowbase = (size_t)bb * S_LEN;
    const size_t vbase   = (size_t)bb * 512 * 4096;

    // Q B-frags: 32 rows, dims [128s, 128s+128)  (resident: 32 VGPR)
    short8 aq[2][4];
#pragma unroll
    for (int mg = 0; mg < 2; ++mg)
#pragma unroll
        for (int kd = 0; kd < 4; ++kd)
            aq[mg][kd] = *(const short8*)(Qg + (rowbase + i0 + mg * 16 + l16) * 512
                                          + s * 128 + kd * 32 + q4 * 8);

    floatx4 oacc[2][4];   // 32 rows x cols [64w, 64w+64)
#pragma unroll
    for (int mg = 0; mg < 2; ++mg)
#pragma unroll
        for (int nc = 0; nc < 4; ++nc) oacc[mg][nc] = (floatx4){0.f, 0.f, 0.f, 0.f};

    const int r = tid >> 4;   // softmax row 0..31
    const int g = tid & 15;   // key pair (2 keys)
    float l_acc = 0.f;

    for (int j0 = hi - 32; j0 >= lo; j0 -= 32) {
        // K + V loads for this step (issued together; consumed after arrival)
        short8 bk[4], vf[4];
#pragma unroll
        for (int kd = 0; kd < 4; ++kd)
            bk[kd] = *(const short8*)(Kg + (rowbase + j0 + h * 16 + l16) * 512
                                      + s * 128 + kd * 32 + q4 * 8);
#pragma unroll
        for (int nc = 0; nc < 4; ++nc)
            vf[nc] = *(const short8*)(Vt + vbase
                + (size_t)(w * 64 + nc * 16 + l16) * 4096 + j0 + q4 * 8);

        // S^T partial: A=K (16 keys), B=Q (16 rows), k=128 dims
        floatx4 sf[2];
#pragma unroll
        for (int mg = 0; mg < 2; ++mg) sf[mg] = (floatx4){0.f, 0.f, 0.f, 0.f};
#pragma unroll
        for (int kd = 0; kd < 4; ++kd)
#pragma unroll
            for (int mg = 0; mg < 2; ++mg)
                sf[mg] = __builtin_amdgcn_mfma_f32_16x16x32_bf16(
                    bk[kd], aq[mg][kd], sf[mg], 0, 0, 0);
        // lane (q4,l16): row = mg*16+l16, keys = h*16+q4*4+{0..3} -> b128 store
#pragma unroll
        for (int mg = 0; mg < 2; ++mg)
            *(floatx4*)&Sred[s][mg * 16 + l16][h * 16 + q4 * 4] = sf[mg];
        __syncthreads();

        // softmax (fixed ref): thread = (row r, keys j0+2g, j0+2g+1)
        float sv0, sv1;
        {
            float2 a0 = *(const float2*)&Sred[0][r][2 * g];
            float2 a1 = *(const float2*)&Sred[1][r][2 * g];
            float2 a2 = *(const float2*)&Sred[2][r][2 * g];
            float2 a3 = *(const float2*)&Sred[3][r][2 * g];
            sv0 = a0.x + a1.x + a2.x + a3.x;
            sv1 = a0.y + a1.y + a2.y + a3.y;
        }
        int key = j0 + 2 * g, row = i0 + r;
        float p0 = (key + 0 >= row) ? __expf(sv0 * scale - MREF) : 0.f;
        float p1 = (key + 1 >= row) ? __expf(sv1 * scale - MREF) : 0.f;
        l_acc += p0 + p1;
        ushort2 pk; pk.x = f2bf(p0); pk.y = f2bf(p1);
        *(ushort2*)&Plds[r][2 * g] = pk;
        __syncthreads();

        // PV: O[32 rows][64w..64w+64) += P * V
        short8 ap[2];
#pragma unroll
        for (int mg = 0; mg < 2; ++mg)
            ap[mg] = *(const short8*)&Plds[mg * 16 + l16][q4 * 8];
#pragma unroll
        for (int mg = 0; mg < 2; ++mg)
#pragma unroll
            for (int nc = 0; nc < 4; ++nc)
                oacc[mg][nc] = __builtin_amdgcn_mfma_f32_16x16x32_bf16(
                    ap[mg], vf[nc], oacc[mg][nc], 0, 0, 0);
        // no trailing barrier: next Sred/Plds writes are ordered behind the
        // next step's barriers relative to this step's reads (see R7 proof)
    }
    __syncthreads();

    // packed slot for this (bb, ch, tile): base = {0,32,96,192} (+320 per batch)
    const int baseArr = (ch == 0) ? 0 : (ch == 1) ? 32 : (ch == 2) ? 96 : 192;
    const int slot = bb * 320 + baseArr + tile;

    Lred[r][g] = l_acc;
    __syncthreads();
    if (tid < 32) {
        float sum = 0.f;
#pragma unroll
        for (int gg = 0; gg < 16; ++gg) sum += Lred[tid][gg];
        Lb[(size_t)slot * 32 + tid] = sum;
    }

    unsigned short* Op = Oh + (size_t)slot * 32 * 512;
#pragma unroll
    for (int mg = 0; mg < 2; ++mg)
#pragma unroll
        for (int nc = 0; nc < 4; ++nc)
#pragma unroll
            for (int rg = 0; rg < 4; ++rg)
                Op[(size_t)(mg * 16 + q4 * 4 + rg) * 512 + w * 64 + nc * 16 + l16]
                    = f2bf(oacc[mg][nc][rg]);
}

// O = (sum_ch Ohat_ch) / (sum_ch l_ch) over valid chunks ch >= i>>10
__global__ __launch_bounds__(256) void flash_merge(
    const unsigned short* __restrict__ Oh, const float* __restrict__ Lb,
    unsigned short* __restrict__ AO)
{
    const int row = blockIdx.x;            // 0..8191
    const int c = threadIdx.x * 2;
    const int bb = row >> 12, i = row & 4095;
    const int t = i >> 5, ri = i & 31;
    const int chmin = i >> 10;
    float lsum = 0.f, v0 = 0.f, v1 = 0.f;
#pragma unroll
    for (int ch = 0; ch < 4; ++ch) {
        if (ch < chmin) continue;
        int baseArr = (ch == 0) ? 0 : (ch == 1) ? 32 : (ch == 2) ? 96 : 192;
        int slot = bb * 320 + baseArr + t;
        lsum += Lb[(size_t)slot * 32 + ri];
        const unsigned short* p = Oh + (size_t)slot * 32 * 512 + (size_t)ri * 512 + c;
        v0 += bf2f(p[0]);
        v1 += bf2f(p[1]);
    }
    float inv = 1.f / lsum;
    ushort2 o; o.x = f2bf(v0 * inv); o.y = f2bf(v1 * inv);
    *(ushort2*)(AO + (size_t)row * 512 + c) = o;
}

static MapArg build_map() {
    int enc[640], steps[640], n = 0;
    for (int bb = 0; bb < 2; ++bb)
        for (int ch = 0; ch < 4; ++ch)
            for (int t = 0; t < 128; ++t) {
                int i0 = 32 * t, lo0 = 1024 * ch, hi = lo0 + 1024;
                if (i0 >= hi) continue;
                int lo = (i0 > lo0) ? i0 : lo0;
                enc[n] = t | (ch << 7) | (bb << 9);
                steps[n] = (hi - lo) / 32;
                ++n;
            }
    // insertion sort DESCENDING by steps
    for (int i = 1; i < n; ++i) {
        int e = enc[i], st = steps[i], j = i - 1;
        while (j >= 0 && steps[j] < st) {
            steps[j + 1] = steps[j]; enc[j + 1] = enc[j]; --j;
        }
        steps[j + 1] = st; enc[j + 1] = e;
    }
    // serpentine placement over assumed round-robin CU = blockIdx % 256
    MapArg mp{};
    for (int k = 0; k < n; ++k) {
        int r = k >> 8, c = k & 255;
        int b = (r & 1) ? (r * 256 + (255 - c)) : (r * 256 + c);
        mp.m[b] = (unsigned short)enc[k];
    }
    return mp;
}

extern "C" void kernel_launch(void* const* d_in, const int* in_sizes, int n_in,
                              void* d_out, int out_size, void* d_ws, size_t ws_size,
                              hipStream_t stream) {
    (void)in_sizes; (void)n_in; (void)out_size; (void)ws_size;
    const float* x  = (const float*)d_in[0];
    const float* Wq = (const float*)d_in[1];
    const float* Wk = (const float*)d_in[2];
    const float* Wv = (const float*)d_in[3];
    const float* Wo = (const float*)d_in[4];
    const float* bo = (const float*)d_in[5];
    float* out = (float*)d_out;

    unsigned short* xb  = (unsigned short*)d_ws;   // 4194304
    unsigned short* Wqb = xb  + 4194304;           // 262144 each
    unsigned short* Wkb = Wqb + 262144;
    unsigned short* Wvb = Wkb + 262144;
    unsigned short* Wob = Wvb + 262144;
    unsigned short* Qb  = Wob + 262144;            // 4194304 each
    unsigned short* Kb  = Qb  + 4194304;
    unsigned short* Vtb = Kb  + 4194304;
    unsigned short* AOb = Vtb + 4194304;
    unsigned short* Ohb = AOb + 4194304;           // packed: 640 slots x 32 x 512
    float* Lbf = (float*)(Ohb + 10485760);         // 640 x 32

    static const MapArg mp = build_map();

    convert_bf16<<<5120, 256, 0, stream>>>(x, Wq, Wk, Wv, Wo, xb);

    gemm_qkv<<<dim3(4, 64, 3), 256, 0, stream>>>(xb, Wqb, Wkb, Wvb, Qb, Kb, Vtb);

    flash_mfma<<<640, 512, 0, stream>>>(Qb, Kb, Vtb, Ohb, Lbf, mp);

    flash_merge<<<8192, 256, 0, stream>>>(Ohb, Lbf, AOb);

    gemm_out<<<dim3(4, 64), 256, 0, stream>>>(AOb, Wob, bo, out);
}

// Round 10
// 274.928 us; speedup vs baseline: 1.0058x; 1.0058x over previous
//
#include <hip/hip_runtime.h>
#include <hip/hip_bf16.h>

#define S_LEN 4096
#define E_DIM 512
#define B_DIM 2
#define M_ROWS (B_DIM * S_LEN)   // 8192

typedef __attribute__((ext_vector_type(8))) short short8;   // 8 bf16 = 4 VGPRs
typedef __attribute__((ext_vector_type(4))) float floatx4;  // MFMA C/D

__device__ __forceinline__ unsigned short f2bf(float f) {
    unsigned u = __float_as_uint(f);
    unsigned r = (u + 0x7fffu + ((u >> 16) & 1u)) >> 16;   // RNE
    return (unsigned short)r;
}
__device__ __forceinline__ float bf2f(unsigned short u) {
    return __uint_as_float((unsigned)u << 16);
}

// async 16B/lane global->LDS (lds dest = wave-uniform base + lane*16)
__device__ __forceinline__ void async_copy16(unsigned short* lds, const unsigned short* g) {
    auto gp = (const __attribute__((address_space(1))) unsigned int*)g;
    auto lp = (__attribute__((address_space(3))) unsigned int*)lds;
    __builtin_amdgcn_global_load_lds(gp, lp, 16, 0, 0);
}

struct MapArg { unsigned short m[320]; };   // encode t | ch<<6 | bb<<8

// ---------------- convert fp32 inputs -> bf16 workspace ----------------
__global__ __launch_bounds__(256) void convert_bf16(
    const float* __restrict__ x,  const float* __restrict__ wq,
    const float* __restrict__ wk, const float* __restrict__ wv,
    const float* __restrict__ wo, unsigned short* __restrict__ dst)
{
    long i = (long)blockIdx.x * 1024 + (long)threadIdx.x * 4;
    const float* src; long off;
    if      (i < 4194304) { src = x;  off = i; }
    else if (i < 4456448) { src = wq; off = i - 4194304; }
    else if (i < 4718592) { src = wk; off = i - 4456448; }
    else if (i < 4980736) { src = wv; off = i - 4718592; }
    else                  { src = wo; off = i - 4980736; }
    float4 v = *(const float4*)(src + off);
    ushort4 o;
    o.x = f2bf(v.x); o.y = f2bf(v.y); o.z = f2bf(v.z); o.w = f2bf(v.w);
    *(ushort4*)(dst + i) = o;
}

// ---------------- MFMA GEMM core: C[m,n] = sum_k A[m,k]*W[n,k] ----------------
__device__ __forceinline__ void gemm_core(
    const unsigned short* __restrict__ A, const unsigned short* __restrict__ W,
    void* __restrict__ Cv, const float* __restrict__ bias, int mode,
    int m0, int n0)
{
    __shared__ unsigned short As[128 * 32];
    __shared__ unsigned short Bs[128 * 32];
    const int tid = threadIdx.x;
    const int lane = tid & 63, wave = tid >> 6;
    const int wm = wave >> 1, wn = wave & 1;
    const int q4 = lane >> 4, l16 = lane & 15;

    floatx4 acc[4][4];
#pragma unroll
    for (int i = 0; i < 4; ++i)
#pragma unroll
        for (int j = 0; j < 4; ++j) acc[i][j] = (floatx4){0.f, 0.f, 0.f, 0.f};

    const int srow = lane >> 2;
    const int scol = (lane & 3) * 8;

    for (int k0 = 0; k0 < 512; k0 += 32) {
        async_copy16(&As[(wave * 16) * 32],
                     A + (size_t)(m0 + wave * 16 + srow) * 512 + k0 + scol);
        async_copy16(&As[(64 + wave * 16) * 32],
                     A + (size_t)(m0 + 64 + wave * 16 + srow) * 512 + k0 + scol);
        async_copy16(&Bs[(wave * 16) * 32],
                     W + (size_t)(n0 + wave * 16 + srow) * 512 + k0 + scol);
        async_copy16(&Bs[(64 + wave * 16) * 32],
                     W + (size_t)(n0 + 64 + wave * 16 + srow) * 512 + k0 + scol);
        __syncthreads();
        short8 af[4], bfr[4];
#pragma unroll
        for (int i = 0; i < 4; ++i) {
            af[i]  = *(const short8*)&As[(wm * 64 + i * 16 + l16) * 32 + q4 * 8];
            bfr[i] = *(const short8*)&Bs[(wn * 64 + i * 16 + l16) * 32 + q4 * 8];
        }
#pragma unroll
        for (int i = 0; i < 4; ++i)
#pragma unroll
            for (int j = 0; j < 4; ++j)
                acc[i][j] = __builtin_amdgcn_mfma_f32_16x16x32_bf16(af[i], bfr[j], acc[i][j], 0, 0, 0);
        __syncthreads();
    }

    if (mode == 0) {
        unsigned short* C = (unsigned short*)Cv;
#pragma unroll
        for (int i = 0; i < 4; ++i) {
            int rowb = m0 + wm * 64 + i * 16 + q4 * 4;
#pragma unroll
            for (int j = 0; j < 4; ++j) {
                int col = n0 + wn * 64 + j * 16 + l16;
#pragma unroll
                for (int rg = 0; rg < 4; ++rg)
                    C[(size_t)(rowb + rg) * 512 + col] = f2bf(acc[i][j][rg]);
            }
        }
    } else if (mode == 1) {
        unsigned short* C = (unsigned short*)Cv;
#pragma unroll
        for (int i = 0; i < 4; ++i) {
            int grow = m0 + wm * 64 + i * 16 + q4 * 4;
            int b = grow >> 12, s = grow & 4095;
#pragma unroll
            for (int j = 0; j < 4; ++j) {
                int e = n0 + wn * 64 + j * 16 + l16;
                ushort4 pk;
                pk.x = f2bf(acc[i][j][0]); pk.y = f2bf(acc[i][j][1]);
                pk.z = f2bf(acc[i][j][2]); pk.w = f2bf(acc[i][j][3]);
                *(ushort4*)(C + (size_t)b * 512 * 4096 + (size_t)e * 4096 + s) = pk;
            }
        }
    } else {
        float* C = (float*)Cv;
#pragma unroll
        for (int i = 0; i < 4; ++i) {
            int rowb = m0 + wm * 64 + i * 16 + q4 * 4;
#pragma unroll
            for (int j = 0; j < 4; ++j) {
                int col = n0 + wn * 64 + j * 16 + l16;
                float bv = bias[col];
#pragma unroll
                for (int rg = 0; rg < 4; ++rg)
                    C[(size_t)(rowb + rg) * 512 + col] = acc[i][j][rg] + bv;
            }
        }
    }
}

__global__ __launch_bounds__(256) void gemm_qkv(
    const unsigned short* __restrict__ xb,
    const unsigned short* __restrict__ Wqb, const unsigned short* __restrict__ Wkb,
    const unsigned short* __restrict__ Wvb,
    unsigned short* __restrict__ Qb, unsigned short* __restrict__ Kb,
    unsigned short* __restrict__ Vtb)
{
    const int z = blockIdx.z;
    const unsigned short* W = (z == 0) ? Wqb : (z == 1) ? Wkb : Wvb;
    unsigned short* C = (z == 0) ? Qb : (z == 1) ? Kb : Vtb;
    gemm_core(xb, W, C, nullptr, (z == 2) ? 1 : 0, blockIdx.y * 128, blockIdx.x * 128);
}

__global__ __launch_bounds__(256) void gemm_out(
    const unsigned short* __restrict__ AOb, const unsigned short* __restrict__ Wob,
    const float* __restrict__ bo, float* __restrict__ out)
{
    gemm_core(AOb, Wob, out, bo, 2, blockIdx.y * 128, blockIdx.x * 128);
}

// ---------------- MFMA flash attention, Tm=64, Tn=32, 1024 thr (16 waves) ----------------
// Anti-causal (keep j >= i). 320 live (tile,batch,chunk-of-1024) blocks via map.
// QK (S^T): wave (d,kh,rh) = dims [128d,+128) x keys [16kh,+16) x rows [32rh,+32);
// fp32 LDS reduce over 4 dim-slices. Fixed softmax ref. PV: wave w owns 32 cols.
// Per-wave regs ~110 <= 128 -> 4 waves/SIMD co-resident within the block.
__global__ __launch_bounds__(1024, 4) void flash_mfma(
    const unsigned short* __restrict__ Qg, const unsigned short* __restrict__ Kg,
    const unsigned short* __restrict__ Vt,
    unsigned short* __restrict__ Oh, float* __restrict__ Lb, MapArg map)
{
    const int enc = map.m[blockIdx.x];
    const int tile = enc & 63, ch = (enc >> 6) & 3, bb = enc >> 8;
    const int i0 = tile * 64;
    const int lo0 = 1024 * ch, hi = 1024 * ch + 1024;
    const int lo = (i0 > lo0) ? i0 : lo0;

    const int tid = threadIdx.x;
    const int lane = tid & 63, w = tid >> 6;
    const int d = w & 3, kh = (w >> 2) & 1, rh = w >> 3;   // dim-slice, key-strip, row-half
    const int q4 = lane >> 4, l16 = lane & 15;
    const float scale = 0.044194173824159216f;  // 1/sqrt(512)
    const float MREF = 4.0f;

    __shared__ float Sred[4][64][36];         // 36.9 KB fp32 S^T partials
    __shared__ unsigned short Plds[64][40];   // 5.1 KB P bf16
    __shared__ float Lred[64][16];

    const size_t rowbase = (size_t)bb * S_LEN;
    const size_t vbase   = (size_t)bb * 512 * 4096;

    // Q B-frags: rows [i0+32rh, +32), dims [128d, +128)  (32 VGPR resident)
    short8 aq[2][4];
#pragma unroll
    for (int mg = 0; mg < 2; ++mg)
#pragma unroll
        for (int kd = 0; kd < 4; ++kd)
            aq[mg][kd] = *(const short8*)(Qg + (rowbase + i0 + rh * 32 + mg * 16 + l16) * 512
                                          + d * 128 + kd * 32 + q4 * 8);

    floatx4 oacc[4][2];   // 64 rows x cols [32w, 32w+32)
#pragma unroll
    for (int mg = 0; mg < 4; ++mg)
#pragma unroll
        for (int nc = 0; nc < 2; ++nc) oacc[mg][nc] = (floatx4){0.f, 0.f, 0.f, 0.f};

    const int r = tid >> 4;   // softmax row 0..63
    const int g = tid & 15;   // key pair (2 keys)
    float l_acc = 0.f;

    for (int j0 = hi - 32; j0 >= lo; j0 -= 32) {
        // V + K loads for this step
        short8 vf[2], bk[4];
#pragma unroll
        for (int nc = 0; nc < 2; ++nc)
            vf[nc] = *(const short8*)(Vt + vbase
                + (size_t)(w * 32 + nc * 16 + l16) * 4096 + j0 + q4 * 8);
#pragma unroll
        for (int kd = 0; kd < 4; ++kd)
            bk[kd] = *(const short8*)(Kg + (rowbase + j0 + kh * 16 + l16) * 512
                                      + d * 128 + kd * 32 + q4 * 8);

        // S^T partial: A=K (16 keys), B=Q (16 rows), k accumulated over 128 dims
        floatx4 sf[2];
#pragma unroll
        for (int mg = 0; mg < 2; ++mg) sf[mg] = (floatx4){0.f, 0.f, 0.f, 0.f};
#pragma unroll
        for (int kd = 0; kd < 4; ++kd)
#pragma unroll
            for (int mg = 0; mg < 2; ++mg)
                sf[mg] = __builtin_amdgcn_mfma_f32_16x16x32_bf16(
                    bk[kd], aq[mg][kd], sf[mg], 0, 0, 0);
        // lane (q4,l16): row = rh*32+mg*16+l16, keys = kh*16+q4*4+{0..3}
#pragma unroll
        for (int mg = 0; mg < 2; ++mg)
            *(floatx4*)&Sred[d][rh * 32 + mg * 16 + l16][kh * 16 + q4 * 4] = sf[mg];
        __syncthreads();

        // softmax (fixed ref): thread = (row r, keys j0+2g, j0+2g+1)
        float sv0, sv1;
        {
            float2 a0 = *(const float2*)&Sred[0][r][2 * g];
            float2 a1 = *(const float2*)&Sred[1][r][2 * g];
            float2 a2 = *(const float2*)&Sred[2][r][2 * g];
            float2 a3 = *(const float2*)&Sred[3][r][2 * g];
            sv0 = a0.x + a1.x + a2.x + a3.x;
            sv1 = a0.y + a1.y + a2.y + a3.y;
        }
        int key = j0 + 2 * g, row = i0 + r;
        float p0 = (key + 0 >= row) ? __expf(sv0 * scale - MREF) : 0.f;
        float p1 = (key + 1 >= row) ? __expf(sv1 * scale - MREF) : 0.f;
        l_acc += p0 + p1;
        ushort2 pk; pk.x = f2bf(p0); pk.y = f2bf(p1);
        *(ushort2*)&Plds[r][2 * g] = pk;
        __syncthreads();

        // PV: O[64 rows][32w..32w+32) += P * V
        short8 ap[4];
#pragma unroll
        for (int mg = 0; mg < 4; ++mg)
            ap[mg] = *(const short8*)&Plds[mg * 16 + l16][q4 * 8];
#pragma unroll
        for (int mg = 0; mg < 4; ++mg)
#pragma unroll
            for (int nc = 0; nc < 2; ++nc)
                oacc[mg][nc] = __builtin_amdgcn_mfma_f32_16x16x32_bf16(
                    ap[mg], vf[nc], oacc[mg][nc], 0, 0, 0);
        // no trailing barrier: next-step Sred/Plds writes are ordered behind
        // the next step's barriers relative to this step's reads
    }
    __syncthreads();

    // packed slot for this (ch, bb, tile)
    const int baseArr = (ch == 0) ? 0 : (ch == 1) ? 32 : (ch == 2) ? 96 : 192;
    const int slot = baseArr + bb * 16 * (ch + 1) + tile;

    Lred[r][g] = l_acc;
    __syncthreads();
    if (tid < 64) {
        float sum = 0.f;
#pragma unroll
        for (int gg = 0; gg < 16; ++gg) sum += Lred[tid][gg];
        Lb[(size_t)slot * 64 + tid] = sum;
    }

    unsigned short* Op = Oh + (size_t)slot * 64 * 512;
#pragma unroll
    for (int mg = 0; mg < 4; ++mg)
#pragma unroll
        for (int nc = 0; nc < 2; ++nc)
#pragma unroll
            for (int rg = 0; rg < 4; ++rg)
                Op[(size_t)(mg * 16 + q4 * 4 + rg) * 512 + w * 32 + nc * 16 + l16]
                    = f2bf(oacc[mg][nc][rg]);
}

// O = (sum_ch Ohat_ch) / (sum_ch l_ch) over valid chunks ch >= i>>10
__global__ __launch_bounds__(256) void flash_merge(
    const unsigned short* __restrict__ Oh, const float* __restrict__ Lb,
    unsigned short* __restrict__ AO)
{
    const int row = blockIdx.x;            // 0..8191
    const int c = threadIdx.x * 2;
    const int bb = row >> 12, i = row & 4095;
    const int t = i >> 6, ri = i & 63;
    const int chmin = i >> 10;
    float lsum = 0.f, v0 = 0.f, v1 = 0.f;
#pragma unroll
    for (int ch = 0; ch < 4; ++ch) {
        if (ch < chmin) continue;
        int baseArr = (ch == 0) ? 0 : (ch == 1) ? 32 : (ch == 2) ? 96 : 192;
        int slot = baseArr + bb * 16 * (ch + 1) + t;
        lsum += Lb[(size_t)slot * 64 + ri];
        const unsigned short* p = Oh + (size_t)slot * 64 * 512 + (size_t)ri * 512 + c;
        v0 += bf2f(p[0]);
        v1 += bf2f(p[1]);
    }
    float inv = 1.f / lsum;
    ushort2 o; o.x = f2bf(v0 * inv); o.y = f2bf(v1 * inv);
    *(ushort2*)(AO + (size_t)row * 512 + c) = o;
}

static MapArg build_map() {
    // collect live blocks with their step counts (Tm=64, 4 chunks of 1024)
    int enc[320], steps[320], n = 0;
    for (int bb = 0; bb < 2; ++bb)
        for (int ch = 0; ch < 4; ++ch)
            for (int t = 0; t < 16 * (ch + 1) && t < 64; ++t) {
                int i0 = t * 64, lo0 = 1024 * ch, hi = lo0 + 1024;
                int lo = (i0 > lo0) ? i0 : lo0;
                enc[n] = t | (ch << 6) | (bb << 8);
                steps[n] = (hi - lo) / 32;
                ++n;
            }
    // insertion sort ascending by steps (stable)
    for (int i = 1; i < n; ++i) {
        int e = enc[i], st = steps[i], j = i - 1;
        while (j >= 0 && steps[j] > st) {
            steps[j + 1] = steps[j]; enc[j + 1] = enc[j]; --j;
        }
        steps[j + 1] = st; enc[j + 1] = e;
    }
    // placement: pairs (c, 256+c) share a CU under round-robin dispatch;
    // ranks 0..127 (partials) pair end-to-end (~34 steps); fulls as singles.
    MapArg mp{};
    for (int c = 0; c < 64; ++c) {
        mp.m[c]       = (unsigned short)enc[127 - c];
        mp.m[256 + c] = (unsigned short)enc[c];
    }
    for (int k = 0; k < 192; ++k)
        mp.m[64 + k] = (unsigned short)enc[128 + k];
    return mp;
}

extern "C" void kernel_launch(void* const* d_in, const int* in_sizes, int n_in,
                              void* d_out, int out_size, void* d_ws, size_t ws_size,
                              hipStream_t stream) {
    (void)in_sizes; (void)n_in; (void)out_size; (void)ws_size;
    const float* x  = (const float*)d_in[0];
    const float* Wq = (const float*)d_in[1];
    const float* Wk = (const float*)d_in[2];
    const float* Wv = (const float*)d_in[3];
    const float* Wo = (const float*)d_in[4];
    const float* bo = (const float*)d_in[5];
    float* out = (float*)d_out;

    unsigned short* xb  = (unsigned short*)d_ws;   // 4194304
    unsigned short* Wqb = xb  + 4194304;           // 262144 each
    unsigned short* Wkb = Wqb + 262144;
    unsigned short* Wvb = Wkb + 262144;
    unsigned short* Wob = Wvb + 262144;
    unsigned short* Qb  = Wob + 262144;            // 4194304 each
    unsigned short* Kb  = Qb  + 4194304;
    unsigned short* Vtb = Kb  + 4194304;
    unsigned short* AOb = Vtb + 4194304;
    unsigned short* Ohb = AOb + 4194304;           // packed: 320 slots x 64 x 512
    float* Lbf = (float*)(Ohb + 10485760);         // 320 x 64

    static const MapArg mp = build_map();

    convert_bf16<<<5120, 256, 0, stream>>>(x, Wq, Wk, Wv, Wo, xb);

    gemm_qkv<<<dim3(4, 64, 3), 256, 0, stream>>>(xb, Wqb, Wkb, Wvb, Qb, Kb, Vtb);

    flash_mfma<<<320, 1024, 0, stream>>>(Qb, Kb, Vtb, Ohb, Lbf, mp);

    flash_merge<<<8192, 256, 0, stream>>>(Ohb, Lbf, AOb);

    gemm_out<<<dim3(4, 64), 256, 0, stream>>>(AOb, Wob, bo, out);
}